// Round 1
// 71.346 us; speedup vs baseline: 1.0981x; 1.0981x over previous
//
#include <hip/hip_runtime.h>

#define NITER 25

// fp64 rcp via v_rcp_f64 + 2 Newton refinements (~1 ulp).
__device__ __forceinline__ double fast_rcp(double x) {
#if __has_builtin(__builtin_amdgcn_rcp)
    double r = __builtin_amdgcn_rcp(x);
    r = fma(fma(-x, r, 1.0), r, r);
    r = fma(fma(-x, r, 1.0), r, r);
    return r;
#else
    return 1.0 / x;
#endif
}

// fp32 rcp (v_rcp_f32, ~1 ulp) — only for fraction-to-boundary ratios.
__device__ __forceinline__ float fast_rcpf(float x) {
#if __has_builtin(__builtin_amdgcn_rcpf)
    return __builtin_amdgcn_rcpf(x);
#else
    return 1.0f / x;
#endif
}

// Per-thread fp64 interior-point LCP, 25 iterations.
//
// 6x6 KKT -> 4x4 Schur system:
//   [[1+D0, 0,    0,    0 ],   [b0]
//    [0,    1+D1, -1,   1 ], = [b1]
//    [0,   -1,    1+D2, 1 ],   [b2]
//    [mu,  -1,   -1,    D3]]   [b3]
// with D_i = s_i/lam_i > 0 strictly (fraction-to-boundary keeps s,lam > 0).
//
// PIVOT-FREE SOLVE (replaces the previous pivoted GE + its ~45 double
// cndmask-swaps per iteration):
//  - Row 0 is diagonal with pivot 1+D0 >= 1:    dl0 = b0/(1+D0).
//  - Exact elimination of row0/col0 (no fill) leaves a 3x3 in dl1..dl3:
//       [[1+D1, -1, 1 ],   [b1]
//        [-1, 1+D2, 1 ], = [b2]
//        [-1,  -1,  D3]]   [b3 - mu*dl0]
//    det = D3*(D1+D2+D1*D2) + (D1+D2) + 4 >= 4 — all-positive form
//    (acm1 = fma(D1,D2,D1+D2) avoids the a*c-1 cancellation), so Cramer
//    is stable with no pivoting: 3 independent numerators, flat DAG.
// Verified algebraically: A*(N1,N2,N3)/det == rhs for random a,c,d,g.
//
// The four 1/lam_i come from ONE fp64 rcp (product trick); lam in
// (1e-30,1e3) keeps the 4-way product far inside fp64 range.
__global__ __launch_bounds__(256) void lcp_kernel(
    const float* __restrict__ pv, const float* __restrict__ mu_p,
    float* __restrict__ out, int n)
{
    int i = blockIdx.x * blockDim.x + threadIdx.x;
    if (i >= n) return;
    const double mu = (double)mu_p[0];
    const double SIG = 0.1;

    const float2 v = ((const float2*)pv)[i];
    const double q0 = -(double)v.x - 2.0;   // q = -v + (-2, 1), MASS=1
    const double q1 = -(double)v.y + 1.0;

    double z0 = -q0, z1 = -q1;
    double lam0 = 1.0, lam1 = 1.0, lam2 = 1.0, lam3 = 1.0;
    double s0 = 1.0, s1 = 1.0, s2 = 1.0, s3 = 1.0;

    for (int it = 0; it < NITER; ++it) {
        // residuals (same formulas as reference)
        double rd0 = z0 + q0 + (lam1 - lam2);
        double rd1 = z1 + q1 - lam0;
        double rp0 = -z1 + s0;
        double rp1 =  z0 + s1 - lam3;
        double rp2 = -z0 + s2 - lam3;
        double rp3 =  s3 - (mu * lam0 - lam1 - lam2);

        double sl0 = s0*lam0, sl1 = s1*lam1, sl2 = s2*lam2, sl3 = s3*lam3;
        double muc = 0.25 * ((sl0 + sl1) + (sl2 + sl3));
        double t = SIG * muc;

        // batched reciprocals: one v_rcp_f64 for all four 1/lam_i
        double p01 = lam0 * lam1, p23 = lam2 * lam3;
        double iP  = fast_rcp(p01 * p23);
        double ip01 = iP * p23, ip23 = iP * p01;
        double il0 = ip01 * lam1, il1 = ip01 * lam0;
        double il2 = ip23 * lam3, il3 = ip23 * lam2;

        double D0 = s0*il0, D1 = s1*il1, D2 = s2*il2, D3 = s3*il3;

        // b = r_pri - r_cent/lam - G*r_dual   (Schur rhs)
        double b0 = rp0 - (sl0 - t)*il0 + rd1;
        double b1 = rp1 - (sl1 - t)*il1 - rd0;
        double b2 = rp2 - (sl2 - t)*il2 + rd0;
        double b3 = rp3 - (sl3 - t)*il3;

        // ---- row 0 (diagonal): dl0 ----
        double ip0 = fast_rcp(1.0 + D0);
        double dl0 = b0 * ip0;

        // ---- 3x3 Cramer (pivot-free, cancellation-free det) ----
        double g3 = fma(-mu, dl0, b3);
        double a = 1.0 + D1, c = 1.0 + D2, d = D3;
        double sD   = D1 + D2;
        double acm1 = fma(D1, D2, sD);          // a*c - 1, exact positive form
        double det  = fma(d, acm1, sD + 4.0);   // >= 4, all terms positive
        double cdp1 = fma(c, d, 1.0);
        double adp1 = fma(a, d, 1.0);
        double dm1  = d - 1.0;
        double cp1  = c + 1.0;
        double ap1  = a + 1.0;
        double N1 = fma(b1, cdp1, fma(b2, dm1, -(g3 * cp1)));
        double N2 = fma(b2, adp1, fma(b1, dm1, -(g3 * ap1)));
        double N3 = fma(g3, acm1, fma(b2, ap1,   b1 * cp1));
        double idet = fast_rcp(det);
        double dl1 = N1 * idet, dl2 = N2 * idet, dl3 = N3 * idet;

        // eliminated-row back-substitution
        double dz0 = -rd0 - dl1 + dl2;
        double dz1 = -rd1 + dl0;

        double ds0 = -rp0 + dz1;
        double ds1 = -rp1 - dz0 + dl3;
        double ds2 = -rp2 + dz0 + dl3;
        double ds3 = -rp3 + (mu * dl0 - dl1 - dl2);

        // fraction-to-boundary: branch condition in fp64 (matches reference),
        // ratio in fp32 via v_rcp_f32
        float amin = 3.0e12f;
        amin = fminf(amin, (dl0 < -1e-12) ? ((float)lam0 * fast_rcpf((float)(-dl0))) : 3.0e12f);
        amin = fminf(amin, (dl1 < -1e-12) ? ((float)lam1 * fast_rcpf((float)(-dl1))) : 3.0e12f);
        amin = fminf(amin, (dl2 < -1e-12) ? ((float)lam2 * fast_rcpf((float)(-dl2))) : 3.0e12f);
        amin = fminf(amin, (dl3 < -1e-12) ? ((float)lam3 * fast_rcpf((float)(-dl3))) : 3.0e12f);
        amin = fminf(amin, (ds0 < -1e-12) ? ((float)s0 * fast_rcpf((float)(-ds0))) : 3.0e12f);
        amin = fminf(amin, (ds1 < -1e-12) ? ((float)s1 * fast_rcpf((float)(-ds1))) : 3.0e12f);
        amin = fminf(amin, (ds2 < -1e-12) ? ((float)s2 * fast_rcpf((float)(-ds2))) : 3.0e12f);
        amin = fminf(amin, (ds3 < -1e-12) ? ((float)s3 * fast_rcpf((float)(-ds3))) : 3.0e12f);
        double alpha = fmin(1.0, 0.99 * (double)amin);

        z0 += alpha * dz0;
        z1 += alpha * dz1;
        lam0 += alpha * dl0; lam1 += alpha * dl1;
        lam2 += alpha * dl2; lam3 += alpha * dl3;
        s0 += alpha * ds0; s1 += alpha * ds1;
        s2 += alpha * ds2; s3 += alpha * ds3;
    }

    ((float2*)out)[i] = make_float2((float)z0, (float)z1);
}

extern "C" void kernel_launch(void* const* d_in, const int* in_sizes, int n_in,
                              void* d_out, int out_size, void* d_ws, size_t ws_size,
                              hipStream_t stream) {
    const float* pv = (const float*)d_in[0];
    const float* mu = (const float*)d_in[1];
    float* out = (float*)d_out;
    int n = in_sizes[0] / 2;  // B = 131072
    int block = 256;
    int grid = (n + block - 1) / block;
    lcp_kernel<<<grid, block, 0, stream>>>(pv, mu, out, n);
}

// Round 2
// 69.607 us; speedup vs baseline: 1.1255x; 1.0250x over previous
//
#include <hip/hip_runtime.h>

#define NITER 25

// fp64 rcp via v_rcp_f64 + 2 Newton refinements (~1 ulp).
__device__ __forceinline__ double fast_rcp(double x) {
#if __has_builtin(__builtin_amdgcn_rcp)
    double r = __builtin_amdgcn_rcp(x);
    r = fma(fma(-x, r, 1.0), r, r);
    r = fma(fma(-x, r, 1.0), r, r);
    return r;
#else
    return 1.0 / x;
#endif
}

// fp32 rcp (v_rcp_f32, ~1 ulp) — only for fraction-to-boundary ratios.
__device__ __forceinline__ float fast_rcpf(float x) {
#if __has_builtin(__builtin_amdgcn_rcpf)
    return __builtin_amdgcn_rcpf(x);
#else
    return 1.0f / x;
#endif
}

// Per-thread fp64 interior-point LCP, 25 iterations.
//
// 4x4 Schur system, DENOMINATOR-CLEARED: multiply Schur row i by lam_i.
// All matrix entries become polynomial in (lam, s) — the 1/lam batch, the
// rcp(1+D0), and rcp(det) chains collapse into ONE fp64 rcp per iteration:
//   row0:  (lam0+s0) dl0 = L0,  L0 = lam0*(rp0+rd1) - (sl0 - t)
//   rows1-3: [[lam1+s1, -lam1, lam1],
//             [-lam2, lam2+s2, lam2],
//             [-lam3, -lam3,   s3 ]] dl = (L1, L2, L3 - mu*lam3*dl0)
//   detM = s3*(s1*s2 + s1*lam2 + lam1*s2)
//        + lam3*(lam1*s2 + s1*lam2 + 4*lam1*lam2)   — all-positive, >= 0,
//   (equals lam1*lam2*lam3*(D3*(D1+D2+D1*D2)+D1+D2+4), same system as the
//   validated unscaled Cramer; numerators verified symbolically + unit test).
//   w = rcp(A0*detM); 1/detM = w*A0; 1/A0 = w*detM.  The rcp input depends
//   only on (lam,s) -> issues right after the state update, in parallel with
//   the rhs chain.
//
// LINEAR-RESIDUAL CARRY: Newton gives exactly r_dual_new = (1-alpha)*r_dual,
// r_pri_new = (1-alpha)*r_pri (linear residuals). Carry rd/rp across
// iterations and scale by (1-alpha) instead of recomputing from state.
__global__ __launch_bounds__(256) void lcp_kernel(
    const float* __restrict__ pv, const float* __restrict__ mu_p,
    float* __restrict__ out, int n)
{
    int i = blockIdx.x * blockDim.x + threadIdx.x;
    if (i >= n) return;
    const double mu = (double)mu_p[0];

    const float2 v = ((const float2*)pv)[i];
    const double q0 = -(double)v.x - 2.0;   // q = -v + (-2, 1), MASS=1
    const double q1 = -(double)v.y + 1.0;

    double z0 = -q0, z1 = -q1;
    double lam0 = 1.0, lam1 = 1.0, lam2 = 1.0, lam3 = 1.0;
    double s0 = 1.0, s1 = 1.0, s2 = 1.0, s3 = 1.0;

    // initial linear residuals (carried; scaled by (1-alpha) each iter)
    double rd0 = z0 + q0 + (lam1 - lam2);
    double rd1 = z1 + q1 - lam0;
    double rp0 = -z1 + s0;
    double rp1 =  z0 + s1 - lam3;
    double rp2 = -z0 + s2 - lam3;
    double rp3 =  s3 - (mu * lam0 - lam1 - lam2);

    for (int it = 0; it < NITER; ++it) {
        double sl0 = s0*lam0, sl1 = s1*lam1, sl2 = s2*lam2, sl3 = s3*lam3;
        double t = 0.025 * ((sl0 + sl1) + (sl2 + sl3));   // SIG * mean(s.lam)

        // scaled Schur rhs L_i = lam_i * b_i (division-free)
        double L0 = fma(lam0, rp0 + rd1, t - sl0);
        double L1 = fma(lam1, rp1 - rd0, t - sl1);
        double L2 = fma(lam2, rp2 + rd0, t - sl2);
        double L3 = fma(lam3, rp3,       t - sl3);

        // scaled-system structural pieces (depend only on lam,s)
        double A0 = lam0 + s0;
        double a1 = lam1 + s1;
        double a2 = lam2 + s2;
        double C3 = fma(s1, s2, fma(s1, lam2, lam1*s2));     // a1*a2 - lam1*lam2
        double inner = fma(2.0, lam1*lam2, fma(lam1, a2, a1*lam2));
        double detM = fma(s3, C3, lam3*inner);               // > 0, no cancellation
        double K1 = fma(a2, s3, lam2*lam3);
        double K2 = fma(a1, s3, lam1*lam3);
        double e3m3 = s3 - lam3;
        double S1 = lam2 + a2;       // m2 + a2
        double S2 = lam1 + a1;       // m1 + a1
        double q1c = lam1 * S1;
        double q2c = lam2 * S2;
        double r1c = lam3 * S2;
        double r2c = lam3 * S1;

        // the single fp64 rcp of the iteration
        double w    = fast_rcp(A0 * detM);
        double idet = w * A0;        // 1/detM
        double iA0  = w * detM;      // 1/A0
        double dl0  = L0 * iA0;
        double R3   = fma(-(mu*lam3), dl0, L3);

        // Cramer numerators (flat DAG)
        double N1 = fma(L1, K1, fma(lam1*L2, e3m3, -(R3*q1c)));
        double N2 = fma(L2, K2, fma(lam2*L1, e3m3, -(R3*q2c)));
        double N3 = fma(R3, C3, fma(L2, r1c, L1*r2c));
        double dl1 = N1*idet, dl2 = N2*idet, dl3 = N3*idet;

        // eliminated-row back-substitution
        double dz0 = -rd0 - dl1 + dl2;
        double dz1 = dl0 - rd1;

        double ds0 = dz1 - rp0;
        double ds1 = (dl3 - dz0) - rp1;
        double ds2 = (dl3 + dz0) - rp2;
        double ds3 = (mu*dl0 - (dl1 + dl2)) - rp3;

        // fraction-to-boundary: condition in fp64 (matches reference),
        // ratio in fp32 via v_rcp_f32; explicit fmin tree
        float r0 = (dl0 < -1e-12) ? ((float)lam0 * fast_rcpf((float)(-dl0))) : 3.0e12f;
        float r1 = (dl1 < -1e-12) ? ((float)lam1 * fast_rcpf((float)(-dl1))) : 3.0e12f;
        float r2 = (dl2 < -1e-12) ? ((float)lam2 * fast_rcpf((float)(-dl2))) : 3.0e12f;
        float r3 = (dl3 < -1e-12) ? ((float)lam3 * fast_rcpf((float)(-dl3))) : 3.0e12f;
        float r4 = (ds0 < -1e-12) ? ((float)s0 * fast_rcpf((float)(-ds0))) : 3.0e12f;
        float r5 = (ds1 < -1e-12) ? ((float)s1 * fast_rcpf((float)(-ds1))) : 3.0e12f;
        float r6 = (ds2 < -1e-12) ? ((float)s2 * fast_rcpf((float)(-ds2))) : 3.0e12f;
        float r7 = (ds3 < -1e-12) ? ((float)s3 * fast_rcpf((float)(-ds3))) : 3.0e12f;
        float m01 = fminf(r0, r1), m23 = fminf(r2, r3);
        float m45 = fminf(r4, r5), m67 = fminf(r6, r7);
        float amin = fminf(fminf(m01, m23), fminf(m45, m67));
        double alpha = fmin(1.0, 0.99 * (double)amin);
        double omal = 1.0 - alpha;

        z0 = fma(alpha, dz0, z0);
        z1 = fma(alpha, dz1, z1);
        lam0 = fma(alpha, dl0, lam0); lam1 = fma(alpha, dl1, lam1);
        lam2 = fma(alpha, dl2, lam2); lam3 = fma(alpha, dl3, lam3);
        s0 = fma(alpha, ds0, s0); s1 = fma(alpha, ds1, s1);
        s2 = fma(alpha, ds2, s2); s3 = fma(alpha, ds3, s3);

        // exact Newton decay of the linear residuals
        rd0 *= omal; rd1 *= omal;
        rp0 *= omal; rp1 *= omal; rp2 *= omal; rp3 *= omal;
    }

    ((float2*)out)[i] = make_float2((float)z0, (float)z1);
}

extern "C" void kernel_launch(void* const* d_in, const int* in_sizes, int n_in,
                              void* d_out, int out_size, void* d_ws, size_t ws_size,
                              hipStream_t stream) {
    const float* pv = (const float*)d_in[0];
    const float* mu = (const float*)d_in[1];
    float* out = (float*)d_out;
    int n = in_sizes[0] / 2;  // B = 131072
    int block = 256;
    int grid = (n + block - 1) / block;
    lcp_kernel<<<grid, block, 0, stream>>>(pv, mu, out, n);
}